// Round 7
// baseline (214.217 us; speedup 1.0000x reference)
//
#include <hip/hip_runtime.h>

#define C_DIM 28
#define HALF 14
#define HW 65536   // 256*256
#define THREADS 256
#define GRID 1024  // 1024*256 threads * 4 px (2 stages x 2 px) = 16*65536 exactly

namespace {

constexpr double K_PI = 3.14159265358979323846;

constexpr double cos_taylor(double u) {
    double u2 = u * u;
    double term = 1.0, sum = 1.0;
    for (int i = 1; i <= 12; ++i) {
        term *= -u2 / (double)((2 * i - 1) * (2 * i));
        sum += term;
    }
    return sum;
}

// cos(pi * t / 56), exact integer range reduction (period 112).
constexpr double cos_pi_over56(int t) {
    t %= 112;
    if (t < 0) t += 112;
    double sign = 1.0;
    if (t > 56) t = 112 - t;
    if (t > 28) { t = 56 - t; sign = -1.0; }
    return sign * cos_taylor(K_PI * (double)t / 56.0);
}

// Symmetry-folded tables.
// D[k][n]    = 2*cos(pi*(2n+1)k/56), n<14.  D[k][27-n] = (-1)^k D[k][n].
// Dinv[n][k] = cos(pi*(2n+1)k/56)*(k==0?0.5:1)/28, n<14.
//              Dinv[27-n][k] = (-1)^k Dinv[n][k].
struct Tables {
    float D[C_DIM][HALF];
    float Dinv[HALF][C_DIM];
};

constexpr Tables make_tables() {
    Tables t{};
    for (int k = 0; k < C_DIM; ++k)
        for (int n = 0; n < HALF; ++n)
            t.D[k][n] = (float)(2.0 * cos_pi_over56((2 * n + 1) * k));
    for (int n = 0; n < HALF; ++n)
        for (int k = 0; k < C_DIM; ++k)
            t.Dinv[n][k] = (float)(cos_pi_over56((2 * n + 1) * k) *
                                   ((k == 0) ? 0.5 : 1.0) / (double)C_DIM);
    return t;
}

constexpr Tables TBL = make_tables();

typedef float f2v __attribute__((ext_vector_type(2)));
typedef float f4v __attribute__((ext_vector_type(4)));

// One 2-pixel DCT->filter->IDCT stage. xv already loaded (28 f2v).
// wrow points at the 2 contiguous weight rows (224 B, L2-hot).
__device__ __forceinline__ void compute_pair(const f2v* __restrict__ xv,
                                             const float* __restrict__ wrow,
                                             float* __restrict__ op) {
    // ---- fold: s[n] = x[n]+x[27-n], u[n] = x[n]-x[27-n]
    f2v s[HALF], u[HALF];
#pragma unroll
    for (int n = 0; n < HALF; ++n) {
        s[n].x = xv[n].x + xv[27 - n].x;
        s[n].y = xv[n].y + xv[27 - n].y;
        u[n].x = xv[n].x - xv[27 - n].x;
        u[n].y = xv[n].y - xv[27 - n].y;
    }

    // ---- weight rows: 448 B contiguous = 14 dwordx4, issued here so the
    // L2-hit latency hides under the forward-DCT FMA block below.
    const f4v* wp4 = (const f4v*)wrow;
    f4v w0[7], w1[7];
#pragma unroll
    for (int q = 0; q < 7; ++q) w0[q] = wp4[q];      // row hw
#pragma unroll
    for (int q = 0; q < 7; ++q) w1[q] = wp4[7 + q];  // row hw+1

    // ---- forward: Xd = D*x via fold. Even k uses s, odd k uses u.
    f2v xd[C_DIM];
#pragma unroll
    for (int k = 0; k < C_DIM; ++k) {
        const float c = TBL.D[k][0];
        xd[k].x = c * ((k & 1) ? u[0].x : s[0].x);
        xd[k].y = c * ((k & 1) ? u[0].y : s[0].y);
    }
#pragma unroll
    for (int n = 1; n < HALF; ++n) {
#pragma unroll
        for (int k = 0; k < C_DIM; ++k) {
            const float c = TBL.D[k][n];
            if (k & 1) {
                xd[k].x = fmaf(c, u[n].x, xd[k].x);
                xd[k].y = fmaf(c, u[n].y, xd[k].y);
            } else {
                xd[k].x = fmaf(c, s[n].x, xd[k].x);
                xd[k].y = fmaf(c, s[n].y, xd[k].y);
            }
        }
    }

    // ---- spectral filter (register transpose is free).
#pragma unroll
    for (int q = 0; q < 7; ++q) {
#pragma unroll
        for (int i = 0; i < 4; ++i) {
            xd[4 * q + i].x *= w0[q][i];
            xd[4 * q + i].y *= w1[q][i];
        }
    }

    // ---- inverse: o = Dinv*xd via fold; o[n]=e+f, o[27-n]=e-f.
    f2v e[HALF], f[HALF];
#pragma unroll
    for (int n = 0; n < HALF; ++n) {
        e[n].x = TBL.Dinv[n][0] * xd[0].x;
        e[n].y = TBL.Dinv[n][0] * xd[0].y;
        f[n].x = TBL.Dinv[n][1] * xd[1].x;
        f[n].y = TBL.Dinv[n][1] * xd[1].y;
    }
#pragma unroll
    for (int j = 1; j < HALF; ++j) {
#pragma unroll
        for (int n = 0; n < HALF; ++n) {
            const float ce = TBL.Dinv[n][2 * j];
            const float cf = TBL.Dinv[n][2 * j + 1];
            e[n].x = fmaf(ce, xd[2 * j].x, e[n].x);
            e[n].y = fmaf(ce, xd[2 * j].y, e[n].y);
            f[n].x = fmaf(cf, xd[2 * j + 1].x, f[n].x);
            f[n].y = fmaf(cf, xd[2 * j + 1].y, f[n].y);
        }
    }

    // ---- stores: 28 dwordx2 (flavor proven irrelevant r2 vs r3).
#pragma unroll
    for (int n = 0; n < HALF; ++n) {
        f2v lo, hi;
        lo.x = e[n].x + f[n].x;  lo.y = e[n].y + f[n].y;
        hi.x = e[n].x - f[n].x;  hi.y = e[n].y - f[n].y;
        *(f2v*)(op + (size_t)n * HW) = lo;
        *(f2v*)(op + (size_t)(27 - n) * HW) = hi;
    }
}

} // namespace

// Thread t: 4 pixels in TWO lane-contiguous 2-px stages of the same b-plane:
//   stage A: (b, q), (b, q+1)           q = (t & 16383)*2
//   stage B: (b, q+32768), (b, q+32769) (second half-plane)
//   b = t >> 14.
// Both stages keep r3/r6's proven 8 B/lane hole-free coalescing and the
// b-outer/hw-inner sweep (FETCH=62.5 MB locality — do not touch).
//
// Round-7 lever: DEPTH-2 SOFTWARE PIPELINE. All 56 x-loads (28 KB/wave)
// issue before the fence; fold-A waits only on batch A (vmcnt~28) while
// batch B flies under stage-A's ~3600-cycle compute; stage B folds with
// zero memory stall. Halves the dead-wait fraction per wave vs r6.
__global__ __launch_bounds__(THREADS, 2) void spedct_kernel(
    const float* __restrict__ x,
    const float* __restrict__ w,
    float* __restrict__ out) {

    const int t   = blockIdx.x * THREADS + threadIdx.x;  // 0..262143
    const int b   = t >> 14;                             // 0..15
    const int hwA = (t & 16383) << 1;                    // 0..32766, even
    const int hwB = hwA + 32768;

    const float* xpA = x   + (size_t)b * C_DIM * HW + hwA;
    const float* xpB = xpA + 32768;
    float*       opA = out + (size_t)b * C_DIM * HW + hwA;
    float*       opB = opA + 32768;

    // ---- both stages' x loads issued back-to-back: 56 dwordx2 NT in flight.
    f2v xa[C_DIM], xb[C_DIM];
#pragma unroll
    for (int n = 0; n < C_DIM; ++n)
        xa[n] = __builtin_nontemporal_load((const f2v*)(xpA + (size_t)n * HW));
#pragma unroll
    for (int n = 0; n < C_DIM; ++n)
        xb[n] = __builtin_nontemporal_load((const f2v*)(xpB + (size_t)n * HW));

    // Batch-issue fence: no load sinks below, no use hoists above.
    asm volatile("" ::: "memory");

    // Stage A: waits only for batch A; batch B keeps flying underneath.
    compute_pair(xa, w + (size_t)hwA * C_DIM, opA);

    // Keep stage-B w-loads from hoisting into stage A's peak-liveness region.
    asm volatile("" ::: "memory");

    // Stage B: batch B arrived during stage-A compute; zero stall.
    compute_pair(xb, w + (size_t)hwB * C_DIM, opB);
}

extern "C" void kernel_launch(void* const* d_in, const int* in_sizes, int n_in,
                              void* d_out, int out_size, void* d_ws, size_t ws_size,
                              hipStream_t stream) {
    const float* x = (const float*)d_in[0];   // [16,28,256,256]
    const float* w = (const float*)d_in[1];   // [256,256,28]
    float* out = (float*)d_out;               // [16,28,256,256]

    spedct_kernel<<<dim3(GRID), dim3(THREADS), 0, stream>>>(x, w, out);
}